// Round 4
// baseline (5348.192 us; speedup 1.0000x reference)
//
#include <hip/hip_runtime.h>
#include <cstdint>
#include <cstddef>

// Problem constants (LSTM_66726611911224)
#define TT   2048
#define BB   64
#define IND  128
#define HH   256
#define GG   1024   // 4*H, gate order i,f,g,o
#define OUTD 128
#define TC   64     // time-chunk size
#define NCH  (TT / TC)   // 32

// ---- workspace layout (bytes), total = 21,925,888 (proven available) ----
static const size_t XG0_OFF    = 0;                         // f16 [TC*B][1024] = 8,388,608
static const size_t XG1_OFF    = 8388608ull;                // f16 [TC*B][1024] = 8,388,608
static const size_t HST0_OFF   = 16777216ull;               // f16 [TC*B][256]  = 2,097,152
static const size_t HST1_OFF   = 18874368ull;               // f16 [TC*B][256]  = 2,097,152
static const size_t WHH_OFF    = 20971520ull;               // uint4 [4][16][512] = 524,288
static const size_t WIH_OFF    = WHH_OFF  + 524288ull;      // uint4 [16384]    =    262,144
static const size_t WOUT_OFF   = WIH_OFF  + 262144ull;      // f16 [128][256]   =     65,536
static const size_t BSUM_OFF   = WOUT_OFF + 65536ull;       // f32 [1024]       =      4,096
static const size_t HSTATE_OFF = BSUM_OFF + 4096ull;        // f16 [64][256]    =     32,768
static const size_t CSTATE_OFF = HSTATE_OFF + 32768ull;     // f32 [64][256]    =     65,536
static const size_t WS_NEEDED  = CSTATE_OFF + 65536ull;     // = 21,925,888

// fused-kernel dynamic LDS: consumer g-weights 128 KB + h ping-pong 1 KB
static const int SMEM_SZ = 131072 + 1024;                   // 132,096 B (<160 KB/CU)

typedef _Float16 h2 __attribute__((ext_vector_type(2)));

union U16 { uint4 u; h2 h[4]; };          // 16B <-> 4x half2
union HU  { unsigned short u; _Float16 h; };

__device__ __forceinline__ float fdot2f(h2 a, h2 b, float c) {
#if __has_builtin(__builtin_amdgcn_fdot2)
  return __builtin_amdgcn_fdot2(a, b, c, false);   // v_dot2_f32_f16, f32 accumulate
#else
  return c + (float)a.x * (float)b.x + (float)a.y * (float)b.y;
#endif
}

__device__ __forceinline__ float sigm(float x) { return 1.f / (1.f + __expf(-x)); }
__device__ __forceinline__ float tanh_fast(float x) {
  float ax = fabsf(x);
  float e  = __expf(-2.f * ax);          // in (0,1], no overflow
  float r  = (1.f - e) / (1.f + e);
  return x < 0.f ? -r : r;
}

// ---------------- K0: pack weights to f16 layouts, bias sum ----------------
// W_hh layout: uint4 index = rr*8192 + q*512 + u2, u2 = u*2+half
//   rr 0/1/2/3 -> rows u / 256+u / 768+u / 512+u  (i, f, o, g)
//   k-range of the uint4: half*128 + q*8 .. +8
__global__ void k0_pack(const float* __restrict__ Whh, const float* __restrict__ Wih,
                        const float* __restrict__ Wout, const float* __restrict__ bih,
                        const float* __restrict__ bhh, uint8_t* __restrict__ ws) {
  int tid = blockIdx.x * 256 + threadIdx.x;
  if (tid < 32768) {
    int rr = tid >> 13, rem = tid & 8191;
    int q = rem >> 9, u2 = rem & 511;
    int u = u2 >> 1, hf = u2 & 1;
    int row = (rr == 0) ? u : (rr == 1) ? 256 + u : (rr == 2) ? 768 + u : 512 + u;
    int kb = hf * 128 + q * 8;
    const float4* s = (const float4*)(Whh + (size_t)row * HH + kb);
    float4 v0 = s[0], v1 = s[1];
    U16 o;
    o.h[0].x = (_Float16)v0.x; o.h[0].y = (_Float16)v0.y;
    o.h[1].x = (_Float16)v0.z; o.h[1].y = (_Float16)v0.w;
    o.h[2].x = (_Float16)v1.x; o.h[2].y = (_Float16)v1.y;
    o.h[3].x = (_Float16)v1.z; o.h[3].y = (_Float16)v1.w;
    ((uint4*)(ws + WHH_OFF))[tid] = o.u;
  } else if (tid < 65536) {                // W_out -> f16, row-major [128][256]
    int t2 = tid - 32768;
    ((_Float16*)(ws + WOUT_OFF))[t2] = (_Float16)Wout[t2];
  } else if (tid < 81920) {                // W_ih -> f16, row-major [1024][128], 8-packed
    int i = tid - 65536;
    const float4* s = (const float4*)(Wih + (size_t)i * 8);
    float4 v0 = s[0], v1 = s[1];
    U16 o;
    o.h[0].x = (_Float16)v0.x; o.h[0].y = (_Float16)v0.y;
    o.h[1].x = (_Float16)v0.z; o.h[1].y = (_Float16)v0.w;
    o.h[2].x = (_Float16)v1.x; o.h[2].y = (_Float16)v1.y;
    o.h[3].x = (_Float16)v1.z; o.h[3].y = (_Float16)v1.w;
    ((uint4*)(ws + WIH_OFF))[i] = o.u;
  } else if (tid < 82944) {                // bias sum
    int n = tid - 81920;
    ((float*)(ws + BSUM_OFF))[n] = bih[n] + bhh[n];
  }
}

// ---------------- K1: xg for chunk 0 only (later chunks made by producer wgs) ----
__global__ void __launch_bounds__(256) k1_xgemm(const float* __restrict__ x,
                                                uint8_t* __restrict__ ws) {
  const uint4* Wp   = (const uint4*)(ws + WIH_OFF);
  const float* bsum = (const float*)(ws + BSUM_OFF);
  _Float16*    xg   = (_Float16*)(ws + XG0_OFF);

  const int s = blockIdx.x >> 4;                       // col segment (64 cols), 16 segs
  const int m = ((blockIdx.x & 15) << 8) + threadIdx.x; // row 0..4095

  __shared__ uint4 wlds[1024];                         // 64 rows x 16 uint4
  __shared__ float bsl[64];
  #pragma unroll
  for (int i = 0; i < 4; ++i)
    wlds[i * 256 + threadIdx.x] = Wp[(size_t)(s << 6) * 16 + i * 256 + threadIdx.x];
  if (threadIdx.x < 64) bsl[threadIdx.x] = bsum[(s << 6) + threadIdx.x];
  __syncthreads();

  const float4* xr = (const float4*)(x + (size_t)m * IND);   // t0 = 0
  h2 xv[64];
  #pragma unroll
  for (int i = 0; i < 32; ++i) {
    float4 v = xr[i];
    xv[2*i  ].x = (_Float16)v.x; xv[2*i  ].y = (_Float16)v.y;
    xv[2*i+1].x = (_Float16)v.z; xv[2*i+1].y = (_Float16)v.w;
  }
  _Float16* xgrow = xg + (size_t)m * GG + (s << 6);
  for (int g = 0; g < 8; ++g) {
    float acc[8];
    #pragma unroll
    for (int j = 0; j < 8; ++j) {
      const uint4* wr = &wlds[(g * 8 + j) * 16];
      float a = bsl[g * 8 + j];
      #pragma unroll
      for (int q = 0; q < 16; ++q) {
        U16 w; w.u = wr[q];
        a = fdot2f(w.h[0], xv[4*q+0], a);
        a = fdot2f(w.h[1], xv[4*q+1], a);
        a = fdot2f(w.h[2], xv[4*q+2], a);
        a = fdot2f(w.h[3], xv[4*q+3], a);
      }
      acc[j] = a;
    }
    U16 o;
    #pragma unroll
    for (int p = 0; p < 4; ++p) { o.h[p].x = (_Float16)acc[2*p]; o.h[p].y = (_Float16)acc[2*p+1]; }
    *(uint4*)(xgrow + g * 8) = o.u;
  }
}

// ---------------- Fused per-chunk kernel: 3 wg roles, 1024 threads ----------------
// grid 144 x 1024 threads:
//   wg 0..63    consumer : recurrence for chunk ch (1 wg per batch element)
//   wg 64..127  producer : xg GEMM for chunk ch+1 (ping-pong buffer)
//   wg 128..143 y        : output projection of chunk ch-1 from hst ping-pong
//
// THIRD SUBMISSION of the round-2 restructure (rounds 2 & 3 were container
// failures; full OOB/deadlock audit found no kernel-side crash mechanism,
// and round-1's timing block showed the harness infra already degraded).
// Theory: consumer is LDS-pipe/overlap-bound at 2 waves/SIMD (observed 4416
// cy/step vs ~2750 cy LDS-pipe work + ~1500 cy VALU floors). 1024 threads
// -> 4 waves/SIMD doubles latency cover; quarter-k (u=tid>>2, qk=tid&3,
// u2g=tid>>1) additionally halves distinct g-rows per wave-instr (adjacent
// lanes broadcast-share each g uint4) -> g-stream ~1536->~768 cy. Per-thread
// weights 96 h2 (i/f/o) fit the 128-reg budget; g stays in 128 KB LDS.
// Quad reduce = shfl_xor(1)+shfl_xor(2), bitwise-identical in all 4 lanes
// (commutative pairs) -> redundant gate computation keeps c coherent
// per-quad, same invariant as the proven lane-pair scheme.
__global__ void __launch_bounds__(1024)
k2_fused(const float* __restrict__ x,
         uint8_t* __restrict__ ws,
         const float* __restrict__ b_out,
         float* __restrict__ out, int ch) {
  extern __shared__ __align__(16) uint8_t smem[];
  const int bi  = blockIdx.x;
  const int tid = threadIdx.x;

  if (bi < 64) {
    // ================= consumer =================
    if (ch >= NCH) return;
    const int b    = bi;
    const int u    = tid >> 2;                        // unit 0..255
    const int qk   = tid & 3;                         // k-quarter
    const int u2g  = (u << 1) + (qk >> 1);            // column in WHH layout
    const int qoff = (qk & 1) << 3;                   // q-offset (0 or 8)
    const int t0   = ch * TC;

    const uint4* WR = (const uint4*)(ws + WHH_OFF);   // [rr][q][u2]
    const uint4* WG = WR + 24576;                     // rr=3 (g rows)
    const unsigned short* xp = (const unsigned short*)(ws + ((ch & 1) ? XG1_OFF : XG0_OFF));
    _Float16* hst    = (_Float16*)(ws + ((ch & 1) ? HST1_OFF : HST0_OFF));
    _Float16* hstate = (_Float16*)(ws + HSTATE_OFF);
    float*    cstate = (float*)(ws + CSTATE_OFF);

    uint4*    gws   = (uint4*)smem;                   // [16][512] uint4 = 128 KB
    _Float16* h_lds = (_Float16*)(smem + 131072);     // [2][256] ping-pong, 1 KB

    // one-time: i/f/o quarter-rows into registers (96 h2)
    h2 wi[32], wf[32], wo[32];
    #pragma unroll
    for (int j = 0; j < 8; ++j) {
      U16 a;
      a.u = WR[(qoff + j) * 512 + u2g];
      wi[4*j+0]=a.h[0]; wi[4*j+1]=a.h[1]; wi[4*j+2]=a.h[2]; wi[4*j+3]=a.h[3];
      a.u = WR[8192 + (qoff + j) * 512 + u2g];
      wf[4*j+0]=a.h[0]; wf[4*j+1]=a.h[1]; wf[4*j+2]=a.h[2]; wf[4*j+3]=a.h[3];
      a.u = WR[16384 + (qoff + j) * 512 + u2g];
      wo[4*j+0]=a.h[0]; wo[4*j+1]=a.h[1]; wo[4*j+2]=a.h[2]; wo[4*j+3]=a.h[3];
    }
    // one-time: stage all g rows into LDS (linear copy, 8192 uint4)
    #pragma unroll
    for (int j = 0; j < 8; ++j) gws[j * 1024 + tid] = WG[j * 1024 + tid];

    if (tid < 32) {                                   // h_{-1} -> buf0
      uint4 z = make_uint4(0u, 0u, 0u, 0u);
      ((uint4*)h_lds)[tid] = (t0 == 0) ? z : ((const uint4*)(hstate + (size_t)b * HH))[tid];
    }
    float c = 0.f;
    if (t0 != 0) c = cstate[(size_t)b * HH + u];      // all 4 lanes of quad same c

    const size_t xrow = (size_t)b * GG;
    HU xi, xf, xgv, xo;
    xi.u  = xp[xrow + u];
    xf.u  = xp[xrow + 256 + u];
    xgv.u = xp[xrow + 512 + u];
    xo.u  = xp[xrow + 768 + u];
    __syncthreads();

    for (int tt = 0; tt < TC; ++tt) {
      float ai = 0.f, af = 0.f, ag = 0.f, ao = 0.f;
      // read h quarter from buf[tt&1]; 4 distinct addrs per wave (broadcast-cheap)
      const uint4* hv = ((const uint4*)h_lds) + (tt & 1) * 32 + qk * 8;
      #pragma unroll
      for (int j = 0; j < 8; ++j) {
        U16 hh;  hh.u  = hv[j];
        U16 wg_; wg_.u = gws[(qoff + j) * 512 + u2g];
        #pragma unroll
        for (int jj = 0; jj < 4; ++jj) {
          ai = fdot2f(wi[4*j+jj], hh.h[jj], ai);
          af = fdot2f(wf[4*j+jj], hh.h[jj], af);
          ag = fdot2f(wg_.h[jj],  hh.h[jj], ag);
          ao = fdot2f(wo[4*j+jj], hh.h[jj], ao);
        }
      }
      // quad reduce over k-quarters; commutative pair sums -> bitwise-identical
      ai += __shfl_xor(ai, 1); ai += __shfl_xor(ai, 2);
      af += __shfl_xor(af, 1); af += __shfl_xor(af, 2);
      ag += __shfl_xor(ag, 1); ag += __shfl_xor(ag, 2);
      ao += __shfl_xor(ao, 1); ao += __shfl_xor(ao, 2);
      float gi = sigm(ai + (float)xi.h);
      float gf = sigm(af + (float)xf.h);
      float gg = tanh_fast(ag + (float)xgv.h);
      float go = sigm(ao + (float)xo.h);
      c = gf * c + gi * gg;
      float hn = go * tanh_fast(c);
      if (qk == 0) {                                  // quarter-0 lanes own stores
        h_lds[((tt + 1) & 1) * HH + u] = (_Float16)hn;
        hst[((size_t)tt * BB + b) * HH + u] = (_Float16)hn;
        if (t0 + tt == TT - 1) {
          const size_t tail = (size_t)TT * BB * OUTD;
          out[tail + (size_t)b * HH + u] = hn;                       // h_T
          out[tail + (size_t)BB * HH + (size_t)b * HH + u] = c;      // c_T
        }
      }
      if (tt + 1 < TC) {                              // prefetch next step's xg
        const size_t nx = xrow + (size_t)(tt + 1) * (BB * GG);
        xi.u  = xp[nx + u];
        xf.u  = xp[nx + 256 + u];
        xgv.u = xp[nx + 512 + u];
        xo.u  = xp[nx + 768 + u];
      }
      __syncthreads();                                // new h visible; old buf free
    }

    // persist state (TC even -> final h is in buf0)
    if (tid < 32) ((uint4*)(hstate + (size_t)b * HH))[tid] = ((const uint4*)h_lds)[tid];
    if (qk == 0) cstate[(size_t)b * HH + u] = c;

  } else if (bi < 128) {
    // ================= producer: xg for chunk ch+1 =================
    if (ch + 1 >= NCH) return;
    const int p    = bi - 64;
    const int seg  = p >> 2;                          // 0..15 (64-col segment)
    const int rowg = p & 3;
    const int m    = rowg * 1024 + tid;               // 0..4095
    const int t0n  = (ch + 1) * TC;

    const uint4* Wp   = (const uint4*)(ws + WIH_OFF);
    const float* bsum = (const float*)(ws + BSUM_OFF);
    _Float16*    xgn  = (_Float16*)(ws + (((ch + 1) & 1) ? XG1_OFF : XG0_OFF));

    uint4* wlds = (uint4*)smem;                       // 1024 uint4 = 16 KB
    float* bsl  = (float*)(smem + 16384);
    wlds[tid] = Wp[(size_t)seg * 1024 + tid];
    if (tid < 64) bsl[tid] = bsum[(seg << 6) + tid];
    __syncthreads();

    const float4* xr = (const float4*)(x + ((size_t)t0n * BB + m) * IND);
    h2 xv[64];
    #pragma unroll
    for (int i = 0; i < 32; ++i) {
      float4 v = xr[i];
      xv[2*i  ].x = (_Float16)v.x; xv[2*i  ].y = (_Float16)v.y;
      xv[2*i+1].x = (_Float16)v.z; xv[2*i+1].y = (_Float16)v.w;
    }
    _Float16* xgrow = xgn + (size_t)m * GG + (seg << 6);
    for (int g = 0; g < 8; ++g) {
      float acc[8];
      #pragma unroll
      for (int j = 0; j < 8; ++j) {
        const uint4* wr = &wlds[(g * 8 + j) * 16];
        float a = bsl[g * 8 + j];
        #pragma unroll
        for (int q = 0; q < 16; ++q) {
          U16 w; w.u = wr[q];
          a = fdot2f(w.h[0], xv[4*q+0], a);
          a = fdot2f(w.h[1], xv[4*q+1], a);
          a = fdot2f(w.h[2], xv[4*q+2], a);
          a = fdot2f(w.h[3], xv[4*q+3], a);
        }
        acc[j] = a;
      }
      U16 o;
      #pragma unroll
      for (int pk = 0; pk < 4; ++pk) { o.h[pk].x = (_Float16)acc[2*pk]; o.h[pk].y = (_Float16)acc[2*pk+1]; }
      *(uint4*)(xgrow + g * 8) = o.u;
    }

  } else {
    // ================= y: output projection for chunk ch-1 =================
    if (ch < 1) return;
    const int seg  = bi - 128;                        // 0..15 (8-col segment)
    const int t0p  = (ch - 1) * TC;

    const _Float16* hstp = (const _Float16*)(ws + (((ch - 1) & 1) ? HST1_OFF : HST0_OFF));
    const uint4* WO = (const uint4*)(ws + WOUT_OFF);  // [128][32] uint4

    uint4* wlds = (uint4*)smem;                       // 256 uint4 = 4 KB
    float* bsl  = (float*)(smem + 4096);
    if (tid < 256) wlds[tid] = WO[(size_t)(seg * 8) * 32 + tid];
    if (tid < 8)   bsl[tid]  = b_out[seg * 8 + tid];
    __syncthreads();

    #pragma unroll
    for (int rr = 0; rr < 4; ++rr) {                  // 4 rows per thread
      const int r = rr * 1024 + tid;                  // 0..4095
      const uint4* hr = (const uint4*)(hstp + (size_t)r * HH);
      float acc[8];
      #pragma unroll
      for (int j = 0; j < 8; ++j) acc[j] = bsl[j];
      #pragma unroll 4
      for (int q = 0; q < 32; ++q) {
        U16 hh; hh.u = hr[q];
        #pragma unroll
        for (int j = 0; j < 8; ++j) {
          U16 w; w.u = wlds[j * 32 + q];
          acc[j] = fdot2f(w.h[0], hh.h[0], acc[j]);
          acc[j] = fdot2f(w.h[1], hh.h[1], acc[j]);
          acc[j] = fdot2f(w.h[2], hh.h[2], acc[j]);
          acc[j] = fdot2f(w.h[3], hh.h[3], acc[j]);
        }
      }
      float* orow = out + ((size_t)t0p * BB + r) * OUTD + seg * 8;
      *(float4*)(orow)     = make_float4(acc[0], acc[1], acc[2], acc[3]);
      *(float4*)(orow + 4) = make_float4(acc[4], acc[5], acc[6], acc[7]);
    }
  }
}

extern "C" void kernel_launch(void* const* d_in, const int* in_sizes, int n_in,
                              void* d_out, int out_size, void* d_ws, size_t ws_size,
                              hipStream_t stream) {
  const float* input = (const float*)d_in[0];
  const float* W_ih  = (const float*)d_in[1];
  const float* W_hh  = (const float*)d_in[2];
  const float* b_ih  = (const float*)d_in[3];
  const float* b_hh  = (const float*)d_in[4];
  const float* W_out = (const float*)d_in[5];
  const float* b_out = (const float*)d_in[6];
  float*   out = (float*)d_out;
  uint8_t* ws  = (uint8_t*)d_ws;

  if (ws_size < WS_NEEDED) return;   // fail validation cleanly instead of faulting

  // allow 129 KB dynamic LDS (gfx950: 160 KB/CU); host-side + idempotent ->
  // safe under graph capture (proven rounds 5 & 8).
  hipFuncSetAttribute((const void*)k2_fused,
                      hipFuncAttributeMaxDynamicSharedMemorySize, SMEM_SZ);

  hipLaunchKernelGGL(k0_pack,  dim3(324), dim3(256), 0, stream,
                     W_hh, W_ih, W_out, b_ih, b_hh, ws);
  hipLaunchKernelGGL(k1_xgemm, dim3(256), dim3(256), 0, stream, input, ws); // chunk 0 xg
  for (int ch = 0; ch <= NCH; ++ch) {   // ch==NCH: only y-role (last chunk's output)
    hipLaunchKernelGGL(k2_fused, dim3(144), dim3(1024), SMEM_SZ, stream,
                       input, ws, b_out, out, ch);
  }
}

// Round 5
// 3700.155 us; speedup vs baseline: 1.4454x; 1.4454x over previous
//
#include <hip/hip_runtime.h>
#include <cstdint>
#include <cstddef>

// Problem constants (LSTM_66726611911224)
#define TT   2048
#define BB   64
#define IND  128
#define HH   256
#define GG   1024   // 4*H, gate order i,f,g,o
#define OUTD 128
#define TC   64     // time-chunk size
#define NCH  (TT / TC)   // 32

// ---- workspace layout (bytes), total = 21,925,888 (proven available) ----
static const size_t XG0_OFF    = 0;                         // f16 [TC*B][1024] = 8,388,608
static const size_t XG1_OFF    = 8388608ull;                // f16 [TC*B][1024] = 8,388,608
static const size_t HST0_OFF   = 16777216ull;               // f16 [TC*B][256]  = 2,097,152
static const size_t HST1_OFF   = 18874368ull;               // f16 [TC*B][256]  = 2,097,152
static const size_t WHH_OFF    = 20971520ull;               // uint4 [4][16][512] = 524,288
static const size_t WIH_OFF    = WHH_OFF  + 524288ull;      // uint4 [16384]    =    262,144
static const size_t WOUT_OFF   = WIH_OFF  + 262144ull;      // f16 [128][256]   =     65,536
static const size_t BSUM_OFF   = WOUT_OFF + 65536ull;       // f32 [1024]       =      4,096
static const size_t HSTATE_OFF = BSUM_OFF + 4096ull;        // f16 [64][256]    =     32,768
static const size_t CSTATE_OFF = HSTATE_OFF + 32768ull;     // f32 [64][256]    =     65,536
static const size_t WS_NEEDED  = CSTATE_OFF + 65536ull;     // = 21,925,888

// fused-kernel dynamic LDS: consumer g-weights 128 KB + h ping-pong 1 KB
static const int SMEM_SZ = 131072 + 1024;                   // 132,096 B (<160 KB/CU)

typedef _Float16 h2 __attribute__((ext_vector_type(2)));

union U16 { uint4 u; h2 h[4]; };          // 16B <-> 4x half2
union HU  { unsigned short u; _Float16 h; };

__device__ __forceinline__ float fdot2f(h2 a, h2 b, float c) {
#if __has_builtin(__builtin_amdgcn_fdot2)
  return __builtin_amdgcn_fdot2(a, b, c, false);   // v_dot2_f32_f16, f32 accumulate
#else
  return c + (float)a.x * (float)b.x + (float)a.y * (float)b.y;
#endif
}

__device__ __forceinline__ float sigm(float x) { return 1.f / (1.f + __expf(-x)); }
__device__ __forceinline__ float tanh_fast(float x) {
  float ax = fabsf(x);
  float e  = __expf(-2.f * ax);          // in (0,1], no overflow
  float r  = (1.f - e) / (1.f + e);
  return x < 0.f ? -r : r;
}

// ---------------- K0: pack weights to f16 layouts, bias sum ----------------
// W_hh layout: uint4 index = rr*8192 + q*512 + u2, u2 = u*2+half
//   rr 0/1/2/3 -> rows u / 256+u / 768+u / 512+u  (i, f, o, g)
//   k-range of the uint4: half*128 + q*8 .. +8
// Consumer lane L has u2 == tid -> all weight/LDS accesses per-lane linear.
__global__ void k0_pack(const float* __restrict__ Whh, const float* __restrict__ Wih,
                        const float* __restrict__ Wout, const float* __restrict__ bih,
                        const float* __restrict__ bhh, uint8_t* __restrict__ ws) {
  int tid = blockIdx.x * 256 + threadIdx.x;
  if (tid < 32768) {
    int rr = tid >> 13, rem = tid & 8191;
    int q = rem >> 9, u2 = rem & 511;
    int u = u2 >> 1, hf = u2 & 1;
    int row = (rr == 0) ? u : (rr == 1) ? 256 + u : (rr == 2) ? 768 + u : 512 + u;
    int kb = hf * 128 + q * 8;
    const float4* s = (const float4*)(Whh + (size_t)row * HH + kb);
    float4 v0 = s[0], v1 = s[1];
    U16 o;
    o.h[0].x = (_Float16)v0.x; o.h[0].y = (_Float16)v0.y;
    o.h[1].x = (_Float16)v0.z; o.h[1].y = (_Float16)v0.w;
    o.h[2].x = (_Float16)v1.x; o.h[2].y = (_Float16)v1.y;
    o.h[3].x = (_Float16)v1.z; o.h[3].y = (_Float16)v1.w;
    ((uint4*)(ws + WHH_OFF))[tid] = o.u;
  } else if (tid < 65536) {                // W_out -> f16, row-major [128][256]
    int t2 = tid - 32768;
    ((_Float16*)(ws + WOUT_OFF))[t2] = (_Float16)Wout[t2];
  } else if (tid < 81920) {                // W_ih -> f16, row-major [1024][128], 8-packed
    int i = tid - 65536;
    const float4* s = (const float4*)(Wih + (size_t)i * 8);
    float4 v0 = s[0], v1 = s[1];
    U16 o;
    o.h[0].x = (_Float16)v0.x; o.h[0].y = (_Float16)v0.y;
    o.h[1].x = (_Float16)v0.z; o.h[1].y = (_Float16)v0.w;
    o.h[2].x = (_Float16)v1.x; o.h[2].y = (_Float16)v1.y;
    o.h[3].x = (_Float16)v1.z; o.h[3].y = (_Float16)v1.w;
    ((uint4*)(ws + WIH_OFF))[i] = o.u;
  } else if (tid < 82944) {                // bias sum
    int n = tid - 81920;
    ((float*)(ws + BSUM_OFF))[n] = bih[n] + bhh[n];
  }
}

// ---------------- K1: xg for chunk 0 only (later chunks made by producer wgs) ----
__global__ void __launch_bounds__(256) k1_xgemm(const float* __restrict__ x,
                                                uint8_t* __restrict__ ws) {
  const uint4* Wp   = (const uint4*)(ws + WIH_OFF);
  const float* bsum = (const float*)(ws + BSUM_OFF);
  _Float16*    xg   = (_Float16*)(ws + XG0_OFF);

  const int s = blockIdx.x >> 4;                       // col segment (64 cols), 16 segs
  const int m = ((blockIdx.x & 15) << 8) + threadIdx.x; // row 0..4095

  __shared__ uint4 wlds[1024];                         // 64 rows x 16 uint4
  __shared__ float bsl[64];
  #pragma unroll
  for (int i = 0; i < 4; ++i)
    wlds[i * 256 + threadIdx.x] = Wp[(size_t)(s << 6) * 16 + i * 256 + threadIdx.x];
  if (threadIdx.x < 64) bsl[threadIdx.x] = bsum[(s << 6) + threadIdx.x];
  __syncthreads();

  const float4* xr = (const float4*)(x + (size_t)m * IND);   // t0 = 0
  h2 xv[64];
  #pragma unroll
  for (int i = 0; i < 32; ++i) {
    float4 v = xr[i];
    xv[2*i  ].x = (_Float16)v.x; xv[2*i  ].y = (_Float16)v.y;
    xv[2*i+1].x = (_Float16)v.z; xv[2*i+1].y = (_Float16)v.w;
  }
  _Float16* xgrow = xg + (size_t)m * GG + (s << 6);
  for (int g = 0; g < 8; ++g) {
    float acc[8];
    #pragma unroll
    for (int j = 0; j < 8; ++j) {
      const uint4* wr = &wlds[(g * 8 + j) * 16];
      float a = bsl[g * 8 + j];
      #pragma unroll
      for (int q = 0; q < 16; ++q) {
        U16 w; w.u = wr[q];
        a = fdot2f(w.h[0], xv[4*q+0], a);
        a = fdot2f(w.h[1], xv[4*q+1], a);
        a = fdot2f(w.h[2], xv[4*q+2], a);
        a = fdot2f(w.h[3], xv[4*q+3], a);
      }
      acc[j] = a;
    }
    U16 o;
    #pragma unroll
    for (int p = 0; p < 4; ++p) { o.h[p].x = (_Float16)acc[2*p]; o.h[p].y = (_Float16)acc[2*p+1]; }
    *(uint4*)(xgrow + g * 8) = o.u;
  }
}

// ---------------- Fused per-chunk kernel: 3 wg roles ----------------
// grid 224 x 512 threads:
//   wg 0..63    consumer : recurrence for chunk ch (1 wg per batch element)
//   wg 64..191  producer : xg GEMM for chunk ch+1 (ping-pong buffer)
//   wg 192..223 y        : output projection of chunk ch-1 from hst ping-pong
//
// ROUND-5 THEORY (from rounds 0/1/4 counter evidence): the i/f/o "register"
// weight arrays were NEVER resident — at VGPR_Count=128 the allocator sinks
// the const loads into the t-loop, re-streaming ~384 KB/CU/step from L2
// (~3000 cy at the ~128 B/cy per-CU L2 link; matches the observed 4416
// cy/step with VALUBusy 22%). Fix: (a) waves_per_eu(2,2) raises the budget
// to 256 regs/wave (8-wave wg -> 2 waves/EU is exact), and (b) asm-pin each
// loaded weight value so it is opaque and cannot be re-materialized/sunk —
// RA must keep 192 h2 live (192 + ~50 working = ~242 <= 256).
__global__ void __launch_bounds__(512)
__attribute__((amdgpu_waves_per_eu(2, 2)))
k2_fused(const float* __restrict__ x,
         uint8_t* __restrict__ ws,
         const float* __restrict__ b_out,
         float* __restrict__ out, int ch) {
  extern __shared__ __align__(16) uint8_t smem[];
  const int bi  = blockIdx.x;
  const int tid = threadIdx.x;

  if (bi < 64) {
    // ================= consumer =================
    if (ch >= NCH) return;
    const int b    = bi;
    const int u    = tid >> 1;                        // unit 0..255
    const int half = tid & 1;                         // k-half
    const int t0   = ch * TC;

    const uint4* WR = (const uint4*)(ws + WHH_OFF);   // [rr][q][u2]
    const uint4* WG = WR + 24576;                     // rr=3 (g rows)
    const unsigned short* xp = (const unsigned short*)(ws + ((ch & 1) ? XG1_OFF : XG0_OFF));
    _Float16* hst    = (_Float16*)(ws + ((ch & 1) ? HST1_OFF : HST0_OFF));
    _Float16* hstate = (_Float16*)(ws + HSTATE_OFF);
    float*    cstate = (float*)(ws + CSTATE_OFF);

    uint4*    gws   = (uint4*)smem;                   // [16][512] uint4 = 128 KB
    _Float16* h_lds = (_Float16*)(smem + 131072);     // [2][256] ping-pong, 1 KB

    // one-time: i/f/o half-rows into registers (192 h2); per-lane linear (u2==tid)
    h2 wi[64], wf[64], wo[64];
    #pragma unroll
    for (int q = 0; q < 16; ++q) {
      U16 a;
      a.u = WR[q * 512 + tid];
      wi[4*q+0]=a.h[0]; wi[4*q+1]=a.h[1]; wi[4*q+2]=a.h[2]; wi[4*q+3]=a.h[3];
      a.u = WR[8192 + q * 512 + tid];
      wf[4*q+0]=a.h[0]; wf[4*q+1]=a.h[1]; wf[4*q+2]=a.h[2]; wf[4*q+3]=a.h[3];
      a.u = WR[16384 + q * 512 + tid];
      wo[4*q+0]=a.h[0]; wo[4*q+1]=a.h[1]; wo[4*q+2]=a.h[2]; wo[4*q+3]=a.h[3];
    }
    // PIN: make every weight value opaque so the compiler cannot sink/remat
    // the loads into the loop (the round-0/1 L2-restream failure mode).
    // Each h2 is one 32-bit VGPR; 192 pins -> RA must hold them live.
    #pragma unroll
    for (int k = 0; k < 64; ++k) {
      asm volatile("" : "+v"(wi[k]));
      asm volatile("" : "+v"(wf[k]));
      asm volatile("" : "+v"(wo[k]));
    }
    // one-time: stage all g rows into LDS (linear copy)
    #pragma unroll
    for (int j = 0; j < 16; ++j) gws[j * 512 + tid] = WG[j * 512 + tid];

    if (tid < 32) {                                   // h_{-1} -> buf0
      uint4 z = make_uint4(0u, 0u, 0u, 0u);
      ((uint4*)h_lds)[tid] = (t0 == 0) ? z : ((const uint4*)(hstate + (size_t)b * HH))[tid];
    }
    float c = 0.f;
    if (t0 != 0) c = cstate[(size_t)b * HH + u];      // both lanes of pair load same c

    const size_t xrow = (size_t)b * GG;
    HU xi, xf, xgv, xo;
    xi.u  = xp[xrow + u];
    xf.u  = xp[xrow + 256 + u];
    xgv.u = xp[xrow + 512 + u];
    xo.u  = xp[xrow + 768 + u];
    __syncthreads();

    for (int tt = 0; tt < TC; ++tt) {
      float ai = 0.f, af = 0.f, ag = 0.f, ao = 0.f;
      // read h from buf[tt&1]; lane's k-half only (2 addresses per wave = free)
      const uint4* hv = ((const uint4*)h_lds) + (tt & 1) * 32 + half * 16;
      #pragma unroll
      for (int q = 0; q < 16; ++q) {
        U16 hh;  hh.u  = hv[q];
        U16 wg_; wg_.u = gws[q * 512 + tid];
        #pragma unroll
        for (int j = 0; j < 4; ++j) {
          ai = fdot2f(wi[4*q+j], hh.h[j], ai);
          af = fdot2f(wf[4*q+j], hh.h[j], af);
          ag = fdot2f(wg_.h[j],  hh.h[j], ag);
          ao = fdot2f(wo[4*q+j], hh.h[j], ao);
        }
      }
      // lane-pair partial exchange (k-half <-> k-half), commutative adds ->
      // both lanes get bitwise-identical sums
      ai += __shfl_xor(ai, 1);
      af += __shfl_xor(af, 1);
      ag += __shfl_xor(ag, 1);
      ao += __shfl_xor(ao, 1);
      float gi = sigm(ai + (float)xi.h);
      float gf = sigm(af + (float)xf.h);
      float gg = tanh_fast(ag + (float)xgv.h);
      float go = sigm(ao + (float)xo.h);
      c = gf * c + gi * gg;
      float hn = go * tanh_fast(c);
      if (half == 0) {                                // even lanes own the stores
        h_lds[((tt + 1) & 1) * HH + u] = (_Float16)hn;
        hst[((size_t)tt * BB + b) * HH + u] = (_Float16)hn;
        if (t0 + tt == TT - 1) {
          const size_t tail = (size_t)TT * BB * OUTD;
          out[tail + (size_t)b * HH + u] = hn;                       // h_T
          out[tail + (size_t)BB * HH + (size_t)b * HH + u] = c;      // c_T
        }
      }
      if (tt + 1 < TC) {                              // prefetch next step's xg
        const size_t nx = xrow + (size_t)(tt + 1) * (BB * GG);
        xi.u  = xp[nx + u];
        xf.u  = xp[nx + 256 + u];
        xgv.u = xp[nx + 512 + u];
        xo.u  = xp[nx + 768 + u];
      }
      __syncthreads();                                // new h visible; old buf free
    }

    // persist state (TC even -> final h is in buf0)
    if (tid < 32) ((uint4*)(hstate + (size_t)b * HH))[tid] = ((const uint4*)h_lds)[tid];
    if (half == 0) cstate[(size_t)b * HH + u] = c;

  } else if (bi < 192) {
    // ================= producer: xg for chunk ch+1 =================
    if (ch + 1 >= NCH) return;
    const int p    = bi - 64;
    const int seg  = p >> 3;                          // 0..15 (64-col segment)
    const int rowg = p & 7;
    const int m    = rowg * 512 + tid;                // 0..4095
    const int t0n  = (ch + 1) * TC;

    const uint4* Wp   = (const uint4*)(ws + WIH_OFF);
    const float* bsum = (const float*)(ws + BSUM_OFF);
    _Float16*    xgn  = (_Float16*)(ws + (((ch + 1) & 1) ? XG1_OFF : XG0_OFF));

    uint4* wlds = (uint4*)smem;                       // 1024 uint4 = 16 KB
    float* bsl  = (float*)(smem + 16384);
    wlds[tid]       = Wp[(size_t)(seg << 6) * 16 + tid];
    wlds[tid + 512] = Wp[(size_t)(seg << 6) * 16 + 512 + tid];
    if (tid < 64) bsl[tid] = bsum[(seg << 6) + tid];
    __syncthreads();

    const float4* xr = (const float4*)(x + ((size_t)t0n * BB + m) * IND);
    h2 xv[64];
    #pragma unroll
    for (int i = 0; i < 32; ++i) {
      float4 v = xr[i];
      xv[2*i  ].x = (_Float16)v.x; xv[2*i  ].y = (_Float16)v.y;
      xv[2*i+1].x = (_Float16)v.z; xv[2*i+1].y = (_Float16)v.w;
    }
    _Float16* xgrow = xgn + (size_t)m * GG + (seg << 6);
    for (int g = 0; g < 8; ++g) {
      float acc[8];
      #pragma unroll
      for (int j = 0; j < 8; ++j) {
        const uint4* wr = &wlds[(g * 8 + j) * 16];
        float a = bsl[g * 8 + j];
        #pragma unroll
        for (int q = 0; q < 16; ++q) {
          U16 w; w.u = wr[q];
          a = fdot2f(w.h[0], xv[4*q+0], a);
          a = fdot2f(w.h[1], xv[4*q+1], a);
          a = fdot2f(w.h[2], xv[4*q+2], a);
          a = fdot2f(w.h[3], xv[4*q+3], a);
        }
        acc[j] = a;
      }
      U16 o;
      #pragma unroll
      for (int pk = 0; pk < 4; ++pk) { o.h[pk].x = (_Float16)acc[2*pk]; o.h[pk].y = (_Float16)acc[2*pk+1]; }
      *(uint4*)(xgrow + g * 8) = o.u;
    }

  } else {
    // ================= y: output projection for chunk ch-1 =================
    if (ch < 1) return;
    const int yb   = bi - 192;                        // 0..31
    const int seg  = yb & 15;                         // 8-col segment
    const int rowg = yb >> 4;                         // 0..1
    const int t0p  = (ch - 1) * TC;

    const _Float16* hstp = (const _Float16*)(ws + (((ch - 1) & 1) ? HST1_OFF : HST0_OFF));
    const uint4* WO = (const uint4*)(ws + WOUT_OFF);  // [128][32] uint4

    uint4* wlds = (uint4*)smem;                       // 256 uint4 = 4 KB
    float* bsl  = (float*)(smem + 4096);
    if (tid < 256) wlds[tid] = WO[(size_t)(seg * 8) * 32 + tid];
    if (tid < 8)   bsl[tid]  = b_out[seg * 8 + tid];
    __syncthreads();

    #pragma unroll
    for (int rr = 0; rr < 4; ++rr) {                  // 4 rows per thread
      const int r = rowg * 2048 + rr * 512 + tid;     // 0..4095
      const uint4* hr = (const uint4*)(hstp + (size_t)r * HH);
      float acc[8];
      #pragma unroll
      for (int j = 0; j < 8; ++j) acc[j] = bsl[j];
      #pragma unroll 4
      for (int q = 0; q < 32; ++q) {
        U16 hh; hh.u = hr[q];
        #pragma unroll
        for (int j = 0; j < 8; ++j) {
          U16 w; w.u = wlds[j * 32 + q];
          acc[j] = fdot2f(w.h[0], hh.h[0], acc[j]);
          acc[j] = fdot2f(w.h[1], hh.h[1], acc[j]);
          acc[j] = fdot2f(w.h[2], hh.h[2], acc[j]);
          acc[j] = fdot2f(w.h[3], hh.h[3], acc[j]);
        }
      }
      float* orow = out + ((size_t)t0p * BB + r) * OUTD + seg * 8;
      *(float4*)(orow)     = make_float4(acc[0], acc[1], acc[2], acc[3]);
      *(float4*)(orow + 4) = make_float4(acc[4], acc[5], acc[6], acc[7]);
    }
  }
}

extern "C" void kernel_launch(void* const* d_in, const int* in_sizes, int n_in,
                              void* d_out, int out_size, void* d_ws, size_t ws_size,
                              hipStream_t stream) {
  const float* input = (const float*)d_in[0];
  const float* W_ih  = (const float*)d_in[1];
  const float* W_hh  = (const float*)d_in[2];
  const float* b_ih  = (const float*)d_in[3];
  const float* b_hh  = (const float*)d_in[4];
  const float* W_out = (const float*)d_in[5];
  const float* b_out = (const float*)d_in[6];
  float*   out = (float*)d_out;
  uint8_t* ws  = (uint8_t*)d_ws;

  if (ws_size < WS_NEEDED) return;   // fail validation cleanly instead of faulting

  // allow 129 KB dynamic LDS (gfx950: 160 KB/CU); host-side + idempotent ->
  // safe under graph capture (proven rounds 5 & 8).
  hipFuncSetAttribute((const void*)k2_fused,
                      hipFuncAttributeMaxDynamicSharedMemorySize, SMEM_SZ);

  hipLaunchKernelGGL(k0_pack,  dim3(324), dim3(256), 0, stream,
                     W_hh, W_ih, W_out, b_ih, b_hh, ws);
  hipLaunchKernelGGL(k1_xgemm, dim3(256), dim3(256), 0, stream, input, ws); // chunk 0 xg
  for (int ch = 0; ch <= NCH; ++ch) {   // ch==NCH: only y-role (last chunk's output)
    hipLaunchKernelGGL(k2_fused, dim3(224), dim3(512), SMEM_SZ, stream,
                       input, ws, b_out, out, ch);
  }
}